// Round 5
// baseline (29.671 us; speedup 1.0000x reference)
//
#include <hip/hip_runtime.h>
#include <math.h>

// STP forward as affine recurrence on r = imu/mu:
//   d[n] = a + (x[n-1]+x[n])/2
//   r[n] = exp(-d[n]) * (r[n-1] + x[n-1]/2) + x[n]/2
// td[n] = (r[n] > 0) ? 1 - r[n] : 1 ; chunk(500)-boundary carry clamp r>0?r:1.
// Carry into a chunk is attenuated by exp(-(500a+trapz)) <= ~7e-13 across the
// chunk, so r_raw[c-1] (which drives the clamp) is a pure function of chunk
// c-1's inputs. Each block therefore recomputes chunk c-1 LOCALLY -> no
// cross-block dependency, no grid sync, single plain kernel.
//
// Block = (chunk c, batch b), 320 thr = 20 seg x 16 u. Per thread:
//   phase 1: TWO interleaved 25-step f64 affine chains (seg s of chunk c-1
//            and of chunk c), factored exp: one deg-11 Taylor per step/chain.
//   LDS scan: r_raw[c-1] (full 20-seg scan) + exclusive prefix (P,Q) for c.
//   phase 2: r_in = P*clamp(r_raw) + Q, 25-step f32 replay (__expf), store.

#define TDIM 50000
#define UDIM 16
#define NCH 100
#define SEG 20      // 25-step sub-segments per chunk
#define SLEN 25
#define NSEQ 128    // B*U

__device__ __forceinline__ float clean(float v) { return (v != v) ? 0.0f : v; }

// exp(y) for |y| <= ~0.7, deg-11 Taylor Horner. abs err < ~2e-12 at 0.55.
__device__ __forceinline__ double exp_small(double y) {
    double p = 2.505210838544172e-8;         // 1/11!
    p = fma(p, y, 2.7557319223985893e-7);    // 1/10!
    p = fma(p, y, 2.755731922398589e-6);     // 1/9!
    p = fma(p, y, 2.48015873015873e-5);      // 1/8!
    p = fma(p, y, 1.984126984126984e-4);     // 1/7!
    p = fma(p, y, 1.3888888888888889e-3);    // 1/6!
    p = fma(p, y, 8.333333333333333e-3);     // 1/5!
    p = fma(p, y, 4.1666666666666664e-2);    // 1/4!
    p = fma(p, y, 1.6666666666666666e-1);    // 1/3!
    p = fma(p, y, 0.5);                      // 1/2!
    p = fma(p, y, 1.0);
    p = fma(p, y, 1.0);
    return p;
}

__global__ __launch_bounds__(320, 4) void stp_one(
    const float* __restrict__ inp, const float* __restrict__ uu,
    const float* __restrict__ tauv, float* __restrict__ out)
{
    const int c = blockIdx.x >> 3;           // chunk 0..99
    const int b = blockIdx.x & 7;            // batch 0..7 (== XCD id)
    const int s = threadIdx.x >> 4;          // seg-in-chunk 0..19
    const int u = threadIdx.x & 15;
    const int cm1 = (c > 0) ? c - 1 : 0;     // c==0: compute junk, discarded
    const int n0R = c   * 500 + s * SLEN;    // own segment start
    const int n0L = cm1 * 500 + s * SLEN;    // recomputed prev-chunk segment

    // Replicate reference f32 -> f64 promotion exactly:
    const float ui   = (fabsf(uu[u]) / 100.0f) * 100.0f;
    const float taui = fmaxf(fabsf(tauv[u]), 0.02001f) * 100.0f;
    const float af   = 1.0f / taui;          // f32 divide (as in reference)
    const double a   = (double)af;
    const double ea  = exp_small(-a);        // a <= 0.4998, in poly range

    const float* pL = inp + ((size_t)b * TDIM + n0L) * UDIM + u;
    const float* pR = inp + ((size_t)b * TDIM + n0R) * UDIM + u;

    // ---- phase 1: two interleaved f64 segment compositions (A,B) ----
    double xpL = (n0L != 0) ? (double)(ui * clean(pL[-UDIM])) : 0.0;
    double xpR = (n0R != 0) ? (double)(ui * clean(pR[-UDIM])) : 0.0;
    double epL = exp_small(-0.5 * xpL);      // exp(-xp/2), carried
    double epR = exp_small(-0.5 * xpR);
    double AL = 1.0, BL = 0.0, AR = 1.0, BR = 0.0;
#pragma unroll 5
    for (int t = 0; t < SLEN; ++t) {
        const double xL  = (double)(ui * clean(pL[(size_t)t * UDIM]));
        const double xR  = (double)(ui * clean(pR[(size_t)t * UDIM]));
        const double exL = exp_small(-0.5 * xL);
        const double exR = exp_small(-0.5 * xR);
        const double eL  = ea * epL * exL;   // exp(-(a + (xp+x)/2))
        const double eR  = ea * epR * exR;
        AL *= eL;  BL = fma(eL, fma(xpL, 0.5, BL), 0.5 * xL);
        AR *= eR;  BR = fma(eR, fma(xpR, 0.5, BR), 0.5 * xR);
        epL = exL; epR = exR; xpL = xL; xpR = xR;
    }

    __shared__ double sAL[SEG][16], sBL[SEG][16];
    __shared__ double sAR[SEG][16], sBR[SEG][16];
    sAL[s][u] = AL; sBL[s][u] = BL;
    sAR[s][u] = AR; sBR[s][u] = BR;
    __syncthreads();

    // raw end of chunk c-1 from r_in = 0 (full 20-seg scan, redundant per s)
    double rp = 0.0;
#pragma unroll
    for (int j = 0; j < SEG; ++j) rp = fma(sAL[j][u], rp, sBL[j][u]);

    // exclusive prefix over own chunk's segs 0..s-1: r_in = P*carry + Q
    double P = 1.0, Q = 0.0;
    for (int j = 0; j < s; ++j) {
        const double Aj = sAR[j][u];
        const double Bj = sBR[j][u];
        P *= Aj;
        Q = fma(Aj, Q, Bj);
    }

    double carry, tdp_d;
    if (c > 0) {
        carry = (rp > 0.0) ? rp : 1.0;       // clamped carry
        tdp_d = (rp > 0.0) ? 1.0 - rp : 1.0; // td from RAW end of prev chunk
    } else {
        carry = 0.0;                          // chunk 0: imu0 = 0
        tdp_d = 1.0;                          // out[0] uses pad value 1.0
    }
    const double r_in = fma(P, carry, Q);
    if (s > 0) tdp_d = (r_in > 0.0) ? 1.0 - r_in : 1.0;

    // ---- phase 2: f32 replay (input L1/L2-hot) ----
    float* o = out + ((size_t)b * TDIM + n0R) * UDIM + u;
    float xpf = (n0R != 0) ? ui * clean(pR[-UDIM]) : 0.0f;
    float r   = (float)r_in;
    float tdp = (float)tdp_d;
#pragma unroll 5
    for (int t = 0; t < SLEN; ++t) {
        const float ts = clean(pR[(size_t)t * UDIM]);
        const float x  = ui * ts;
        const float d  = af + (xpf + x) * 0.5f;
        const float e  = __expf(-d);
        r = e * (r + xpf * 0.5f) + x * 0.5f;
        o[(size_t)t * UDIM] = ts * tdp;      // out[n] = tstim[n]*td[n-1]
        tdp = (r > 0.0f) ? 1.0f - r : 1.0f;
        xpf = x;
    }
}

extern "C" void kernel_launch(void* const* d_in, const int* in_sizes, int n_in,
                              void* d_out, int out_size, void* d_ws, size_t ws_size,
                              hipStream_t stream) {
    const float* inp  = (const float*)d_in[0];
    const float* uu   = (const float*)d_in[1];
    const float* tauv = (const float*)d_in[2];
    float* out = (float*)d_out;

    stp_one<<<dim3(NCH * 8), dim3(320), 0, stream>>>(inp, uu, tauv, out);
}